// Round 8
// baseline (233.240 us; speedup 1.0000x reference)
//
#include <hip/hip_runtime.h>
#include <cstdint>
#include <cstddef>

#define B_ 4
#define T_ 2048
#define C_ 1024
#define M_ (B_ * T_)   // 8192 rows
#define QKV_STRIDE 3072
#define NT 32          // K-tiles of BK=32 (both GEMMs, K=1024)

typedef unsigned short u16;
typedef _Float16 half8 __attribute__((ext_vector_type(8)));
typedef float f32x16 __attribute__((ext_vector_type(16)));
typedef unsigned short ushort8v __attribute__((ext_vector_type(8)));

__device__ __forceinline__ ushort4 cvt4(float4 v) {
    ushort4 o;
    _Float16 a = (_Float16)v.x; o.x = __builtin_bit_cast(unsigned short, a);
    _Float16 b = (_Float16)v.y; o.y = __builtin_bit_cast(unsigned short, b);
    _Float16 c = (_Float16)v.z; o.z = __builtin_bit_cast(unsigned short, c);
    _Float16 d = (_Float16)v.w; o.w = __builtin_bit_cast(unsigned short, d);
    return o;
}

// ================= fragment-major layout =================
// chunk (mt, ks) = 1KB at ((mt*64 + ks)*512) u16; lane l holds
// Mat[row = mt*32 + (l&31)][k = ks*16 + (l>>5)*8 + e].
// V-frag (PV B-operand): element [tok][ch] at
//   ((tok>>4)*32 + (ch>>5))*512 + ((ch&31) + 32*((tok>>3)&1))*8 + (tok&7)

// ---------------- prologue: coalesced LDS-transpose to frag-major --------
__global__ void prologue2(const float* __restrict__ x,
                          const float* __restrict__ Wq, const float* __restrict__ Wk,
                          const float* __restrict__ Wv, const float* __restrict__ Wo,
                          const float* __restrict__ bq, const float* __restrict__ bk,
                          const float* __restrict__ bv,
                          u16* __restrict__ xf, u16* __restrict__ wfq,
                          u16* __restrict__ wfo, float* __restrict__ bcat) {
    const int blk = blockIdx.x;
    const int tid = threadIdx.x;
    if (blk >= 3072) {
        int i = (blk - 3072) * 256 + tid;
        const float* src = (i < 1024) ? bq : (i < 2048) ? bk : bv;
        bcat[i] = src[i & 1023];
        return;
    }
    __shared__ ushort8v g16[512];   // 32 rows x 16 granules, XOR-swizzled
    const float* src;
    u16* dst;
    size_t chunk_base;
    int kg;
    if (blk < 2048) {
        const int mt = blk >> 3; kg = blk & 7;
        src = x + (size_t)mt * 32 * C_;
        dst = xf; chunk_base = (size_t)mt * 64;
    } else {
        const int w = blk - 2048;
        const int mat = w >> 8, nt = (w >> 3) & 31; kg = w & 7;
        src = ((mat == 0) ? Wq : (mat == 1) ? Wk : (mat == 2) ? Wv : Wo)
              + (size_t)nt * 32 * C_;
        if (mat < 3) { dst = wfq; chunk_base = (size_t)(mat * 32 + nt) * 64; }
        else         { dst = wfo; chunk_base = (size_t)nt * 64; }
    }
    const int r = tid >> 3, gc = (tid & 7) * 2;
    const float4* s4 = (const float4*)(src + (size_t)r * C_ + kg * 128 + (tid & 7) * 16);
    float4 f0 = s4[0], f1 = s4[1], f2 = s4[2], f3 = s4[3];
    ushort4 h0 = cvt4(f0), h1 = cvt4(f1), h2 = cvt4(f2), h3 = cvt4(f3);
    ushort8v ga, gb;
    ga[0]=h0.x; ga[1]=h0.y; ga[2]=h0.z; ga[3]=h0.w;
    ga[4]=h1.x; ga[5]=h1.y; ga[6]=h1.z; ga[7]=h1.w;
    gb[0]=h2.x; gb[1]=h2.y; gb[2]=h2.z; gb[3]=h2.w;
    gb[4]=h3.x; gb[5]=h3.y; gb[6]=h3.z; gb[7]=h3.w;
    g16[r * 16 + ((gc    ) ^ (r & 15))] = ga;
    g16[r * 16 + ((gc + 1) ^ (r & 15))] = gb;
    __syncthreads();
    const int lane = tid & 63, rr = lane & 31, hi = lane >> 5;
#pragma unroll
    for (int r2 = 0; r2 < 2; ++r2) {
        const int ksl = r2 * 4 + (tid >> 6);
        const int g = ksl * 2 + hi;
        ushort8v v = g16[rr * 16 + (g ^ (rr & 15))];
        *(ushort8v*)(dst + ((chunk_base + kg * 8 + ksl) * 64 + lane) * 8) = v;
    }
}

#define AS1_ __attribute__((address_space(1)))
#define AS3_ __attribute__((address_space(3)))

__device__ __forceinline__ void gload16(const u16* g, u16* l) {
    __builtin_amdgcn_global_load_lds((AS1_ void*)g, (AS3_ void*)l, 16, 0, 0);
}

#define MFMA_ __builtin_amdgcn_mfma_f32_32x32x16_f16
#define LD8_(p) (*(const half8*)(p))

// ---------------- gemm_p2 (proven, 60.5us QKV): BM=256xBN=128xBK=32 -------
#define STAGE(NB, KT) { const size_t ko = (size_t)(KT) * 1024;            \
    gload16(gA0 + ko, (NB) + lA0); gload16(gA1 + ko, (NB) + lA1);         \
    gload16(gA2 + ko, (NB) + lA2); gload16(gA3 + ko, (NB) + lA3);         \
    gload16(gB0 + ko, (NB) + lB0); gload16(gB1 + ko, (NB) + lB1); }

#define TILE(CB, NB, KT, DOSTG, VW)                                        \
  {                                                                        \
    half8 a0 = *(const half8*)((CB) + oA);                                 \
    half8 a1 = *(const half8*)((CB) + oA + 1024);                          \
    half8 a2 = *(const half8*)((CB) + oA + 2048);                          \
    half8 a3 = *(const half8*)((CB) + oA + 3072);                          \
    half8 b0v = *(const half8*)((CB) + oB);                                \
    half8 b1v = *(const half8*)((CB) + oB + 1024);                         \
    if (DOSTG) STAGE(NB, (KT) + 2);                                        \
    __builtin_amdgcn_s_setprio(1);                                         \
    acc00 = MFMA_(a0, b0v, acc00, 0, 0, 0);                                \
    acc01 = MFMA_(a0, b1v, acc01, 0, 0, 0);                                \
    acc10 = MFMA_(a1, b0v, acc10, 0, 0, 0);                                \
    acc11 = MFMA_(a1, b1v, acc11, 0, 0, 0);                                \
    acc20 = MFMA_(a2, b0v, acc20, 0, 0, 0);                                \
    acc21 = MFMA_(a2, b1v, acc21, 0, 0, 0);                                \
    acc30 = MFMA_(a3, b0v, acc30, 0, 0, 0);                                \
    acc31 = MFMA_(a3, b1v, acc31, 0, 0, 0);                                \
    __builtin_amdgcn_s_setprio(0);                                         \
    a0 = *(const half8*)((CB) + oA + 512);                                 \
    a1 = *(const half8*)((CB) + oA + 1536);                                \
    a2 = *(const half8*)((CB) + oA + 2560);                                \
    a3 = *(const half8*)((CB) + oA + 3584);                                \
    b0v = *(const half8*)((CB) + oB + 512);                                \
    b1v = *(const half8*)((CB) + oB + 1536);                               \
    __builtin_amdgcn_s_setprio(1);                                         \
    acc00 = MFMA_(a0, b0v, acc00, 0, 0, 0);                                \
    acc01 = MFMA_(a0, b1v, acc01, 0, 0, 0);                                \
    acc10 = MFMA_(a1, b0v, acc10, 0, 0, 0);                                \
    acc11 = MFMA_(a1, b1v, acc11, 0, 0, 0);                                \
    acc20 = MFMA_(a2, b0v, acc20, 0, 0, 0);                                \
    acc21 = MFMA_(a2, b1v, acc21, 0, 0, 0);                                \
    acc30 = MFMA_(a3, b0v, acc30, 0, 0, 0);                                \
    acc31 = MFMA_(a3, b1v, acc31, 0, 0, 0);                                \
    __builtin_amdgcn_s_setprio(0);                                         \
    if ((VW) == 6)      asm volatile("s_waitcnt vmcnt(6) lgkmcnt(0)" ::: "memory"); \
    else if ((VW) == 0) asm volatile("s_waitcnt vmcnt(0) lgkmcnt(0)" ::: "memory"); \
    else                asm volatile("s_waitcnt lgkmcnt(0)" ::: "memory"); \
    asm volatile("s_barrier" ::: "memory");                                \
  }

__global__ __launch_bounds__(256, 2) void gemm_p2(
    const u16* __restrict__ Afrag, const u16* __restrict__ Bfrag,
    const float* __restrict__ bias, u16* __restrict__ Cout, int Ndim)
{
    __shared__ u16 lds[3][12288];
    const int tid  = threadIdx.x;
    const int lane = tid & 63;
    const int wave = tid >> 6;
    const int wm   = wave >> 1;
    const int wn   = wave & 1;
    const int la8  = lane * 8;

    const int nb  = gridDim.x * gridDim.y;
    int bid = blockIdx.y * gridDim.x + blockIdx.x;
    bid = (bid & 7) * (nb >> 3) + (bid >> 3);
    const int bx = bid % gridDim.x;
    const int by = bid / gridDim.x;

    const u16* gA0 = Afrag + ((size_t)(by*8 + ((wave    )>>1))*64 + ((wave    )&1))*512 + la8;
    const u16* gA1 = Afrag + ((size_t)(by*8 + ((wave+ 4 )>>1))*64 + ((wave+ 4 )&1))*512 + la8;
    const u16* gA2 = Afrag + ((size_t)(by*8 + ((wave+ 8 )>>1))*64 + ((wave+ 8 )&1))*512 + la8;
    const u16* gA3 = Afrag + ((size_t)(by*8 + ((wave+12 )>>1))*64 + ((wave+12 )&1))*512 + la8;
    const u16* gB0 = Bfrag + ((size_t)(bx*4 + ((wave    )>>1))*64 + ((wave    )&1))*512 + la8;
    const u16* gB1 = Bfrag + ((size_t)(bx*4 + ((wave+ 4 )>>1))*64 + ((wave+ 4 )&1))*512 + la8;
    const int lA0 = (wave     ) * 512;
    const int lA1 = (wave +  4) * 512;
    const int lA2 = (wave +  8) * 512;
    const int lA3 = (wave + 12) * 512;
    const int lB0 = 8192 + (wave    ) * 512;
    const int lB1 = 8192 + (wave + 4) * 512;

    const int oA = wm * 4096 + la8;
    const int oB = 8192 + wn * 2048 + la8;

    u16* b0 = &lds[0][0];
    u16* b1 = &lds[1][0];
    u16* b2 = &lds[2][0];

    STAGE(b0, 0);
    STAGE(b1, 1);
    asm volatile("s_waitcnt vmcnt(6)" ::: "memory");
    asm volatile("s_barrier" ::: "memory");

    f32x16 acc00, acc01, acc10, acc11, acc20, acc21, acc30, acc31;
#pragma unroll
    for (int r = 0; r < 16; ++r) {
        acc00[r] = 0.f; acc01[r] = 0.f; acc10[r] = 0.f; acc11[r] = 0.f;
        acc20[r] = 0.f; acc21[r] = 0.f; acc30[r] = 0.f; acc31[r] = 0.f;
    }

#pragma unroll 1
    for (int kt = 0; kt < NT - 2; kt += 3) {
        TILE(b0, b2, kt,     1, 6);
        TILE(b1, b0, kt + 1, 1, 6);
        TILE(b2, b1, kt + 2, 1, 6);
    }
    TILE(b0, b2, NT - 2, 0, 0);
    TILE(b1, b2, NT - 1, 0, -1);

    const int m0 = by * 256 + wm * 128;
    const int n0 = bx * 128 + wn * 64;
    f32x16 accs[4][2] = {{acc00, acc01}, {acc10, acc11}, {acc20, acc21}, {acc30, acc31}};
#pragma unroll
    for (int i = 0; i < 4; ++i) {
#pragma unroll
        for (int j = 0; j < 2; ++j) {
            const int col = n0 + j * 32 + (lane & 31);
            const float bv = bias[col];
#pragma unroll
            for (int reg = 0; reg < 16; ++reg) {
                const int row = m0 + i * 32 + (reg & 3) + 8 * (reg >> 2) + 4 * (lane >> 5);
                _Float16 h = (_Float16)(accs[i][j][reg] + bv);
                Cout[(size_t)row * Ndim + col] = __builtin_bit_cast(unsigned short, h);
            }
        }
    }
}

// ---------------- gemm_s (proven r5): BM=128 x BN=128, 512 blocks = 2/CU --
#define STAGE_S0(NB, KO) { gload16(gA0 + (KO), (NB) + lsA0); gload16(gB0 + (KO), (NB) + lsB0); }
#define STAGE_S1(NB, KO) { gload16(gA1 + (KO), (NB) + lsA1); gload16(gB1 + (KO), (NB) + lsB1); }

#define TILE_S(CB, NB, KT, DOSTG, VW)                                      \
  {                                                                        \
    const size_t ko = (size_t)((KT) + 2) * 1024;                           \
    half8 a0 = *(const half8*)((CB) + oA);                                 \
    half8 a1 = *(const half8*)((CB) + oA + 1024);                          \
    half8 b0v = *(const half8*)((CB) + oB);                                \
    half8 b1v = *(const half8*)((CB) + oB + 1024);                         \
    if (DOSTG) STAGE_S0(NB, ko);                                           \
    __builtin_amdgcn_s_setprio(1);                                         \
    acc00 = MFMA_(a0, b0v, acc00, 0, 0, 0);                                \
    acc01 = MFMA_(a0, b1v, acc01, 0, 0, 0);                                \
    acc10 = MFMA_(a1, b0v, acc10, 0, 0, 0);                                \
    acc11 = MFMA_(a1, b1v, acc11, 0, 0, 0);                                \
    __builtin_amdgcn_s_setprio(0);                                         \
    a0 = *(const half8*)((CB) + oA + 512);                                 \
    a1 = *(const half8*)((CB) + oA + 1536);                                \
    b0v = *(const half8*)((CB) + oB + 512);                                \
    b1v = *(const half8*)((CB) + oB + 1536);                               \
    if (DOSTG) STAGE_S1(NB, ko);                                           \
    __builtin_amdgcn_s_setprio(1);                                         \
    acc00 = MFMA_(a0, b0v, acc00, 0, 0, 0);                                \
    acc01 = MFMA_(a0, b1v, acc01, 0, 0, 0);                                \
    acc10 = MFMA_(a1, b0v, acc10, 0, 0, 0);                                \
    acc11 = MFMA_(a1, b1v, acc11, 0, 0, 0);                                \
    __builtin_amdgcn_s_setprio(0);                                         \
    if ((VW) == 4)      asm volatile("s_waitcnt vmcnt(4) lgkmcnt(0)" ::: "memory"); \
    else if ((VW) == 0) asm volatile("s_waitcnt vmcnt(0) lgkmcnt(0)" ::: "memory"); \
    else                asm volatile("s_waitcnt lgkmcnt(0)" ::: "memory"); \
    asm volatile("s_barrier" ::: "memory");                                \
  }

__global__ __launch_bounds__(256, 2) void gemm_s(
    const u16* __restrict__ Afrag, const u16* __restrict__ Bfrag,
    const float* __restrict__ bias, float* __restrict__ Cout, int Ndim)
{
    __shared__ u16 lds[3][8192];
    const int tid  = threadIdx.x;
    const int lane = tid & 63;
    const int wave = tid >> 6;
    const int wm   = wave >> 1;
    const int wn   = wave & 1;
    const int la8  = lane * 8;

    const int nb  = gridDim.x * gridDim.y;
    int bid = blockIdx.y * gridDim.x + blockIdx.x;
    bid = (bid & 7) * (nb >> 3) + (bid >> 3);
    const int bx = bid % gridDim.x;
    const int by = bid / gridDim.x;

    const u16* gA0 = Afrag + ((size_t)(by*4 + ((wave    )>>1))*64 + ((wave    )&1))*512 + la8;
    const u16* gA1 = Afrag + ((size_t)(by*4 + ((wave+ 4 )>>1))*64 + ((wave+ 4 )&1))*512 + la8;
    const u16* gB0 = Bfrag + ((size_t)(bx*4 + ((wave    )>>1))*64 + ((wave    )&1))*512 + la8;
    const u16* gB1 = Bfrag + ((size_t)(bx*4 + ((wave+ 4 )>>1))*64 + ((wave+ 4 )&1))*512 + la8;
    const int lsA0 = (wave    ) * 512;
    const int lsA1 = (wave + 4) * 512;
    const int lsB0 = 4096 + (wave    ) * 512;
    const int lsB1 = 4096 + (wave + 4) * 512;

    const int oA = wm * 2048 + la8;
    const int oB = 4096 + wn * 2048 + la8;

    u16* b0 = &lds[0][0];
    u16* b1 = &lds[1][0];
    u16* b2 = &lds[2][0];

    STAGE_S0(b0, 0); STAGE_S1(b0, 0);
    STAGE_S0(b1, 1024); STAGE_S1(b1, 1024);
    asm volatile("s_waitcnt vmcnt(4)" ::: "memory");
    asm volatile("s_barrier" ::: "memory");

    f32x16 acc00, acc01, acc10, acc11;
#pragma unroll
    for (int r = 0; r < 16; ++r) { acc00[r] = 0.f; acc01[r] = 0.f; acc10[r] = 0.f; acc11[r] = 0.f; }

#pragma unroll 1
    for (int kt = 0; kt < NT - 2; kt += 3) {
        TILE_S(b0, b2, kt,     1, 4);
        TILE_S(b1, b0, kt + 1, 1, 4);
        TILE_S(b2, b1, kt + 2, 1, 4);
    }
    TILE_S(b0, b2, NT - 2, 0, 0);
    TILE_S(b1, b2, NT - 1, 0, -1);

    const int m0 = by * 128 + wm * 64;
    const int n0 = bx * 128 + wn * 64;
    f32x16 accs[2][2] = {{acc00, acc01}, {acc10, acc11}};
#pragma unroll
    for (int i = 0; i < 2; ++i) {
#pragma unroll
        for (int j = 0; j < 2; ++j) {
            const int col = n0 + j * 32 + (lane & 31);
            const float bv = bias[col];
#pragma unroll
            for (int reg = 0; reg < 16; ++reg) {
                const int row = m0 + i * 32 + (reg & 3) + 8 * (reg >> 2) + 4 * (lane >> 5);
                Cout[(size_t)row * Ndim + col] = accs[i][j][reg] + bv;
            }
        }
    }
}

// ---------------- vfmt: row-major V section -> V-frag (prologue2 pattern) -
// Per block: 32 tokens x 128 ch. Coalesced 16B reads -> XOR-swizzled LDS ->
// coalesced 1KB frag-chunk stores. Mapping verified against attn's V loads:
// chunk = (tok>>4)*32 + (ch>>5); interior = ((ch&31)+32*((tok>>3)&1))*8+(tok&7).
__global__ __launch_bounds__(256) void vfmt(
    const u16* __restrict__ qkv, u16* __restrict__ vf)
{
    __shared__ ushort8v g16[512];   // [32 tok][16 granules], swizzled
    const int blk = blockIdx.x;     // 2048 = 256 tokblk x 8 chblk
    const int tid = threadIdx.x;
    const int tb = blk >> 3, cb = blk & 7;
    const int r = tid >> 3;                 // token row 0..31
    const int gc = (tid & 7) * 2;           // granule pair
    const u16* src = qkv + (size_t)(tb * 32 + r) * QKV_STRIDE + 2048 + cb * 128 + (tid & 7) * 16;
    ushort8v ga = *(const ushort8v*)src;
    ushort8v gb = *(const ushort8v*)(src + 8);
    g16[r * 16 + ((gc    ) ^ (r & 15))] = ga;
    g16[r * 16 + ((gc + 1) ^ (r & 15))] = gb;
    __syncthreads();
    const int lane = tid & 63, wave = tid >> 6, hi = lane >> 5;
#pragma unroll
    for (int r2 = 0; r2 < 2; ++r2) {
        const int k = wave + 4 * r2;        // chunk-local 0..7
        // lane l, elem e: tok_local = 16*(k>>2) + 8*hi + e ; ch_local = (k&3)*32 + (lane&31)
        const int cl = (k & 3) * 32 + (lane & 31);
        const int gi = cl >> 3, sub = cl & 7;
        const int tbase = 16 * (k >> 2) + 8 * hi;
        ushort8v outv;
#pragma unroll
        for (int e = 0; e < 8; ++e) {
            const int tl = tbase + e;
            outv[e] = ((const u16*)&g16[tl * 16 + (gi ^ (tl & 15))])[sub];
        }
        const size_t chunk = (size_t)tb * 64 + (k >> 2) * 32 + cb * 4 + (k & 3);
        *(ushort8v*)(vf + chunk * 512 + lane * 8) = outv;
    }
}

// ---------------- attn_rm: MFMA attention from row-major Q/K + V-frag -----
// Round-6 verified core (swapped QK^T, per-lane softmax, P-pack, PV, ctx
// store) with Q/K operands gathered DIRECTLY from row-major qkvh:
// A-frag lane l = K[clamp(t0+shift+(l&31))][ks*16 + (l>>5)*8 + e]
// B-frag lane l = Q[t0+(l&31)][ks*16 + (l>>5)*8 + e]  -- 16B/lane gathers.
__global__ __launch_bounds__(64) void attn_rm(
    const u16* __restrict__ qkv, const u16* __restrict__ vf,
    u16* __restrict__ ctxf)
{
    const int l   = threadIdx.x;
    const int q   = l & 31;
    const int hi  = l >> 5;
    const int t0  = blockIdx.x * 32;
    const int t0l = t0 & (T_ - 1);

    // ---- QK^T (two shifted 32-row K tiles) ----
    const int r1 = min(max(t0 - 16 + q, 0), M_ - 1);
    const int r2 = min(max(t0 + 16 + q, 0), M_ - 1);
    const u16* a1p = qkv + (size_t)r1 * QKV_STRIDE + 1024 + hi * 8;
    const u16* a2p = qkv + (size_t)r2 * QKV_STRIDE + 1024 + hi * 8;
    const u16* qp  = qkv + (size_t)(t0 + q) * QKV_STRIDE + hi * 8;

    f32x16 sc1, sc2;
#pragma unroll
    for (int r = 0; r < 16; ++r) { sc1[r] = 0.f; sc2[r] = 0.f; }
#pragma unroll 8
    for (int ks = 0; ks < 64; ++ks) {
        half8 a1 = LD8_(a1p + ks * 16);
        half8 a2 = LD8_(a2p + ks * 16);
        half8 qb = LD8_(qp  + ks * 16);
        sc1 = MFMA_(a1, qb, sc1, 0, 0, 0);
        sc2 = MFMA_(a2, qb, sc2, 0, 0, 0);
    }

    // ---- merge half-split columns via lane^32 ----
    float px1[16], px2[16];
#pragma unroll
    for (int r = 0; r < 16; ++r) {
        px1[r] = __shfl_xor(sc1[r], 32);
        px2[r] = __shfl_xor(sc2[r], 32);
    }

    // ---- assemble s[p], p = j_abs - (t0-16); mask + scale ----
    const int plo = max(q + 8, 16 - t0l);
    const int phi = min(q + 24, (T_ + 15) - t0l);
    float s[64];
#pragma unroll
    for (int p = 0; p < 64; ++p) {
        const int row = p & 31;
        const int h   = (row >> 2) & 1;
        const int rg  = (row & 3) + 4 * (row >> 3);
        const float own = (p < 32) ? sc1[rg] : sc2[rg];
        const float oth = (p < 32) ? px1[rg] : px2[rg];
        const float v = (h == hi) ? own : oth;
        s[p] = (p >= plo && p <= phi) ? v * 0.03125f : -3.0e38f;
    }

    // ---- per-lane softmax ----
    float mx = s[0];
#pragma unroll
    for (int p = 1; p < 64; ++p) mx = fmaxf(mx, s[p]);
    float den = 0.f;
#pragma unroll
    for (int p = 0; p < 64; ++p) { const float w = __expf(s[p] - mx); s[p] = w; den += w; }
    const float inv = 1.f / den;

    // ---- pack P -> fp16 A-frags ----
    half8 pa0, pa1, pa2, pa3;
#pragma unroll
    for (int e = 0; e < 8; ++e) {
        pa0[e] = (_Float16)((hi ? s[ 8 + e] : s[ 0 + e]) * inv);
        pa1[e] = (_Float16)((hi ? s[24 + e] : s[16 + e]) * inv);
        pa2[e] = (_Float16)((hi ? s[40 + e] : s[32 + e]) * inv);
        pa3[e] = (_Float16)((hi ? s[56 + e] : s[48 + e]) * inv);
    }

    // ---- PV: 4 token-16 k-slices x 32 ch-chunks; ctx -> A-frag-major ----
    const int s0i = (t0 - 16) >> 4;
    const u16* vb0p = vf + (size_t)min(max(s0i    , 0), M_/16 - 1) * 16384 + l * 8;
    const u16* vb1p = vf + (size_t)min(max(s0i + 1, 0), M_/16 - 1) * 16384 + l * 8;
    const u16* vb2p = vf + (size_t)min(max(s0i + 2, 0), M_/16 - 1) * 16384 + l * 8;
    const u16* vb3p = vf + (size_t)min(max(s0i + 3, 0), M_/16 - 1) * 16384 + l * 8;
    const size_t ctxb = (size_t)(t0 >> 5) * 32768;
    const int lpo = 32 * ((l >> 3) & 1);
    const int e7  = l & 7;
#pragma unroll 2
    for (int n = 0; n < 32; ++n) {
        half8 v0 = LD8_(vb0p + n * 512);
        half8 v1 = LD8_(vb1p + n * 512);
        half8 v2 = LD8_(vb2p + n * 512);
        half8 v3 = LD8_(vb3p + n * 512);
        f32x16 o;
#pragma unroll
        for (int r = 0; r < 16; ++r) o[r] = 0.f;
        o = MFMA_(pa0, v0, o, 0, 0, 0);
        o = MFMA_(pa1, v1, o, 0, 0, 0);
        o = MFMA_(pa2, v2, o, 0, 0, 0);
        o = MFMA_(pa3, v3, o, 0, 0, 0);
        u16* cp = ctxf + ctxb + (size_t)(2 * n + (q >> 4)) * 512 + e7;
#pragma unroll
        for (int r = 0; r < 16; ++r) {
            const int mrow = (r & 3) + 8 * (r >> 2) + 4 * hi;
            _Float16 hv = (_Float16)o[r];
            cp[(mrow + lpo) * 8] = __builtin_bit_cast(unsigned short, hv);
        }
    }
}

// ---------------- host launch ----------------
extern "C" void kernel_launch(void* const* d_in, const int* in_sizes, int n_in,
                              void* d_out, int out_size, void* d_ws, size_t ws_size,
                              hipStream_t stream) {
    const float* x  = (const float*)d_in[0];
    const float* Wq = (const float*)d_in[1];
    const float* bq = (const float*)d_in[2];
    const float* Wk = (const float*)d_in[3];
    const float* bk = (const float*)d_in[4];
    const float* Wv = (const float*)d_in[5];
    const float* bv = (const float*)d_in[6];
    const float* Wo = (const float*)d_in[7];
    const float* bo = (const float*)d_in[8];
    float* out = (float*)d_out;

    const size_t MC = (size_t)M_ * C_;              // 8M u16
    u16* xf   = (u16*)d_ws;                         // 8M  (x frag; dead after QKV GEMM)
    u16* wfq  = xf   + MC;                          // 3M  (Wq;Wk;Wv frag)
    u16* wfo  = wfq  + 3 * (size_t)C_ * C_;         // 1M  (Wo frag)
    u16* qkvh = wfo  + (size_t)C_ * C_;             // 24M (row-major qkv)
    u16* ctxf = qkvh + (size_t)M_ * QKV_STRIDE;     // 8M  (frag-major)
    float* bcat = (float*)(ctxf + MC);              // 3072 floats
    u16* vf   = xf;                                 // 8M, aliases dead xf

    prologue2<<<3084, 256, 0, stream>>>(x, Wq, Wk, Wv, Wo, bq, bk, bv,
                                        xf, wfq, wfo, bcat);

    dim3 gqkv(QKV_STRIDE / 128, M_ / 256);   // (24, 32) = 768 blocks, 2/CU
    gemm_p2<<<gqkv, 256, 0, stream>>>(xf, wfq, bcat, qkvh, QKV_STRIDE);

    vfmt<<<2048, 256, 0, stream>>>(qkvh, vf);

    attn_rm<<<M_ / 32, 64, 0, stream>>>(qkvh, vf, ctxf);

    dim3 go(C_ / 128, M_ / 128);             // (8, 64) = 512 blocks, 2/CU
    gemm_s<<<go, 256, 0, stream>>>(ctxf, wfo, bo, out, C_);
}

// Round 9
// 228.831 us; speedup vs baseline: 1.0193x; 1.0193x over previous
//
#include <hip/hip_runtime.h>
#include <cstdint>
#include <cstddef>

#define B_ 4
#define T_ 2048
#define C_ 1024
#define M_ (B_ * T_)   // 8192 rows
#define QK_STRIDE 2048
#define NT 32          // K-tiles of BK=32 (both GEMMs, K=1024)

typedef unsigned short u16;
typedef _Float16 half8 __attribute__((ext_vector_type(8)));
typedef float f32x16 __attribute__((ext_vector_type(16)));
typedef unsigned short ushort8v __attribute__((ext_vector_type(8)));

__device__ __forceinline__ ushort4 cvt4(float4 v) {
    ushort4 o;
    _Float16 a = (_Float16)v.x; o.x = __builtin_bit_cast(unsigned short, a);
    _Float16 b = (_Float16)v.y; o.y = __builtin_bit_cast(unsigned short, b);
    _Float16 c = (_Float16)v.z; o.z = __builtin_bit_cast(unsigned short, c);
    _Float16 d = (_Float16)v.w; o.w = __builtin_bit_cast(unsigned short, d);
    return o;
}

// ================= layouts =================
// frag chunk (mt, ks) = 1KB at ((mt*64+ks)*512) u16; lane l holds
// Mat[row=mt*32+(l&31)][k=ks*16+(l>>5)*8+e].
// V-frag (PV B-operand): element [tok][ch] at
//   ((tok>>4)*32 + (ch>>5))*512 + ((ch&31) + 32*((tok>>3)&1))*8 + (tok&7)
// qkh: row-major [M][2048] = Q(0..1023) | K(1024..2047) per row.

// ---------------- prologue: coalesced LDS-transpose to frag-major --------
__global__ void prologue2(const float* __restrict__ x,
                          const float* __restrict__ Wq, const float* __restrict__ Wk,
                          const float* __restrict__ Wv, const float* __restrict__ Wo,
                          const float* __restrict__ bq, const float* __restrict__ bk,
                          const float* __restrict__ bv,
                          u16* __restrict__ xf, u16* __restrict__ wfq,
                          u16* __restrict__ wfo, float* __restrict__ bcat) {
    const int blk = blockIdx.x;
    const int tid = threadIdx.x;
    if (blk >= 3072) {
        int i = (blk - 3072) * 256 + tid;
        const float* src = (i < 1024) ? bq : (i < 2048) ? bk : bv;
        bcat[i] = src[i & 1023];
        return;
    }
    __shared__ ushort8v g16[512];   // 32 rows x 16 granules, XOR-swizzled
    const float* src;
    u16* dst;
    size_t chunk_base;
    int kg;
    if (blk < 2048) {
        const int mt = blk >> 3; kg = blk & 7;
        src = x + (size_t)mt * 32 * C_;
        dst = xf; chunk_base = (size_t)mt * 64;
    } else {
        const int w = blk - 2048;
        const int mat = w >> 8, nt = (w >> 3) & 31; kg = w & 7;
        src = ((mat == 0) ? Wq : (mat == 1) ? Wk : (mat == 2) ? Wv : Wo)
              + (size_t)nt * 32 * C_;
        if (mat < 3) { dst = wfq; chunk_base = (size_t)(mat * 32 + nt) * 64; }
        else         { dst = wfo; chunk_base = (size_t)nt * 64; }
    }
    const int r = tid >> 3, gc = (tid & 7) * 2;
    const float4* s4 = (const float4*)(src + (size_t)r * C_ + kg * 128 + (tid & 7) * 16);
    float4 f0 = s4[0], f1 = s4[1], f2 = s4[2], f3 = s4[3];
    ushort4 h0 = cvt4(f0), h1 = cvt4(f1), h2 = cvt4(f2), h3 = cvt4(f3);
    ushort8v ga, gb;
    ga[0]=h0.x; ga[1]=h0.y; ga[2]=h0.z; ga[3]=h0.w;
    ga[4]=h1.x; ga[5]=h1.y; ga[6]=h1.z; ga[7]=h1.w;
    gb[0]=h2.x; gb[1]=h2.y; gb[2]=h2.z; gb[3]=h2.w;
    gb[4]=h3.x; gb[5]=h3.y; gb[6]=h3.z; gb[7]=h3.w;
    g16[r * 16 + ((gc    ) ^ (r & 15))] = ga;
    g16[r * 16 + ((gc + 1) ^ (r & 15))] = gb;
    __syncthreads();
    const int lane = tid & 63, rr = lane & 31, hi = lane >> 5;
#pragma unroll
    for (int r2 = 0; r2 < 2; ++r2) {
        const int ksl = r2 * 4 + (tid >> 6);
        const int g = ksl * 2 + hi;
        ushort8v v = g16[rr * 16 + (g ^ (rr & 15))];
        *(ushort8v*)(dst + ((chunk_base + kg * 8 + ksl) * 64 + lane) * 8) = v;
    }
}

#define AS1_ __attribute__((address_space(1)))
#define AS3_ __attribute__((address_space(3)))

__device__ __forceinline__ void gload16(const u16* g, u16* l) {
    __builtin_amdgcn_global_load_lds((AS1_ void*)g, (AS3_ void*)l, 16, 0, 0);
}

#define MFMA_ __builtin_amdgcn_mfma_f32_32x32x16_f16
#define LD8_(p) (*(const half8*)(p))

// ---------------- gemm_p2 (proven QKV loop): BM=256xBN=128xBK=32 ----------
// Epilogue: bx<16 -> Q/K row-major [M][2048]; bx>=16 -> V-frag DIRECT.
// V-frag store derivation: C regs 4r..4r+3 = 4 consecutive tokens; interior
// ((ch&31)+32*(r&1))*8 + 4*hi + delta -> one ushort4 (8B) per r, and lanes
// (lane&31, hi) tile a contiguous 1KB run => fully coalesced, cheaper than
// the row-major write it replaces. Kills the vfmt kernel.
#define STAGE(NB, KT) { const size_t ko = (size_t)(KT) * 1024;            \
    gload16(gA0 + ko, (NB) + lA0); gload16(gA1 + ko, (NB) + lA1);         \
    gload16(gA2 + ko, (NB) + lA2); gload16(gA3 + ko, (NB) + lA3);         \
    gload16(gB0 + ko, (NB) + lB0); gload16(gB1 + ko, (NB) + lB1); }

#define TILE(CB, NB, KT, DOSTG, VW)                                        \
  {                                                                        \
    half8 a0 = *(const half8*)((CB) + oA);                                 \
    half8 a1 = *(const half8*)((CB) + oA + 1024);                          \
    half8 a2 = *(const half8*)((CB) + oA + 2048);                          \
    half8 a3 = *(const half8*)((CB) + oA + 3072);                          \
    half8 b0v = *(const half8*)((CB) + oB);                                \
    half8 b1v = *(const half8*)((CB) + oB + 1024);                         \
    if (DOSTG) STAGE(NB, (KT) + 2);                                        \
    __builtin_amdgcn_s_setprio(1);                                         \
    acc00 = MFMA_(a0, b0v, acc00, 0, 0, 0);                                \
    acc01 = MFMA_(a0, b1v, acc01, 0, 0, 0);                                \
    acc10 = MFMA_(a1, b0v, acc10, 0, 0, 0);                                \
    acc11 = MFMA_(a1, b1v, acc11, 0, 0, 0);                                \
    acc20 = MFMA_(a2, b0v, acc20, 0, 0, 0);                                \
    acc21 = MFMA_(a2, b1v, acc21, 0, 0, 0);                                \
    acc30 = MFMA_(a3, b0v, acc30, 0, 0, 0);                                \
    acc31 = MFMA_(a3, b1v, acc31, 0, 0, 0);                                \
    __builtin_amdgcn_s_setprio(0);                                         \
    a0 = *(const half8*)((CB) + oA + 512);                                 \
    a1 = *(const half8*)((CB) + oA + 1536);                                \
    a2 = *(const half8*)((CB) + oA + 2560);                                \
    a3 = *(const half8*)((CB) + oA + 3584);                                \
    b0v = *(const half8*)((CB) + oB + 512);                                \
    b1v = *(const half8*)((CB) + oB + 1536);                               \
    __builtin_amdgcn_s_setprio(1);                                         \
    acc00 = MFMA_(a0, b0v, acc00, 0, 0, 0);                                \
    acc01 = MFMA_(a0, b1v, acc01, 0, 0, 0);                                \
    acc10 = MFMA_(a1, b0v, acc10, 0, 0, 0);                                \
    acc11 = MFMA_(a1, b1v, acc11, 0, 0, 0);                                \
    acc20 = MFMA_(a2, b0v, acc20, 0, 0, 0);                                \
    acc21 = MFMA_(a2, b1v, acc21, 0, 0, 0);                                \
    acc30 = MFMA_(a3, b0v, acc30, 0, 0, 0);                                \
    acc31 = MFMA_(a3, b1v, acc31, 0, 0, 0);                                \
    __builtin_amdgcn_s_setprio(0);                                         \
    if ((VW) == 6)      asm volatile("s_waitcnt vmcnt(6) lgkmcnt(0)" ::: "memory"); \
    else if ((VW) == 0) asm volatile("s_waitcnt vmcnt(0) lgkmcnt(0)" ::: "memory"); \
    else                asm volatile("s_waitcnt lgkmcnt(0)" ::: "memory"); \
    asm volatile("s_barrier" ::: "memory");                                \
  }

__global__ __launch_bounds__(256, 2) void gemm_p2(
    const u16* __restrict__ Afrag, const u16* __restrict__ Bfrag,
    const float* __restrict__ bias, u16* __restrict__ qkh,
    u16* __restrict__ vf)
{
    __shared__ u16 lds[3][12288];
    const int tid  = threadIdx.x;
    const int lane = tid & 63;
    const int wave = tid >> 6;
    const int wm   = wave >> 1;
    const int wn   = wave & 1;
    const int la8  = lane * 8;

    const int nb  = gridDim.x * gridDim.y;
    int bid = blockIdx.y * gridDim.x + blockIdx.x;
    bid = (bid & 7) * (nb >> 3) + (bid >> 3);
    const int bx = bid % gridDim.x;
    const int by = bid / gridDim.x;

    const u16* gA0 = Afrag + ((size_t)(by*8 + ((wave    )>>1))*64 + ((wave    )&1))*512 + la8;
    const u16* gA1 = Afrag + ((size_t)(by*8 + ((wave+ 4 )>>1))*64 + ((wave+ 4 )&1))*512 + la8;
    const u16* gA2 = Afrag + ((size_t)(by*8 + ((wave+ 8 )>>1))*64 + ((wave+ 8 )&1))*512 + la8;
    const u16* gA3 = Afrag + ((size_t)(by*8 + ((wave+12 )>>1))*64 + ((wave+12 )&1))*512 + la8;
    const u16* gB0 = Bfrag + ((size_t)(bx*4 + ((wave    )>>1))*64 + ((wave    )&1))*512 + la8;
    const u16* gB1 = Bfrag + ((size_t)(bx*4 + ((wave+ 4 )>>1))*64 + ((wave+ 4 )&1))*512 + la8;
    const int lA0 = (wave     ) * 512;
    const int lA1 = (wave +  4) * 512;
    const int lA2 = (wave +  8) * 512;
    const int lA3 = (wave + 12) * 512;
    const int lB0 = 8192 + (wave    ) * 512;
    const int lB1 = 8192 + (wave + 4) * 512;

    const int oA = wm * 4096 + la8;
    const int oB = 8192 + wn * 2048 + la8;

    u16* b0 = &lds[0][0];
    u16* b1 = &lds[1][0];
    u16* b2 = &lds[2][0];

    STAGE(b0, 0);
    STAGE(b1, 1);
    asm volatile("s_waitcnt vmcnt(6)" ::: "memory");
    asm volatile("s_barrier" ::: "memory");

    f32x16 acc00, acc01, acc10, acc11, acc20, acc21, acc30, acc31;
#pragma unroll
    for (int r = 0; r < 16; ++r) {
        acc00[r] = 0.f; acc01[r] = 0.f; acc10[r] = 0.f; acc11[r] = 0.f;
        acc20[r] = 0.f; acc21[r] = 0.f; acc30[r] = 0.f; acc31[r] = 0.f;
    }

#pragma unroll 1
    for (int kt = 0; kt < NT - 2; kt += 3) {
        TILE(b0, b2, kt,     1, 6);
        TILE(b1, b0, kt + 1, 1, 6);
        TILE(b2, b1, kt + 2, 1, 6);
    }
    TILE(b0, b2, NT - 2, 0, 0);
    TILE(b1, b2, NT - 1, 0, -1);

    // C/D: col = lane&31, row = (reg&3)+8*(reg>>2)+4*(lane>>5)  [m74/m101]
    const int m0 = by * 256 + wm * 128;
    const int n0 = bx * 128 + wn * 64;
    const int hi = lane >> 5;
    f32x16 accs[4][2] = {{acc00, acc01}, {acc10, acc11}, {acc20, acc21}, {acc30, acc31}};
    if (bx < 16) {          // ---- Q/K: row-major [M][2048] ----
#pragma unroll
        for (int i = 0; i < 4; ++i) {
#pragma unroll
            for (int j = 0; j < 2; ++j) {
                const int col = n0 + j * 32 + (lane & 31);
                const float bv = bias[col];
#pragma unroll
                for (int reg = 0; reg < 16; ++reg) {
                    const int row = m0 + i * 32 + (reg & 3) + 8 * (reg >> 2) + 4 * hi;
                    _Float16 h = (_Float16)(accs[i][j][reg] + bv);
                    qkh[(size_t)row * QK_STRIDE + col] = __builtin_bit_cast(unsigned short, h);
                }
            }
        }
    } else {                // ---- V: V-frag direct, coalesced 8B stores ----
#pragma unroll
        for (int i = 0; i < 4; ++i) {
#pragma unroll
            for (int j = 0; j < 2; ++j) {
                const int col = n0 + j * 32 + (lane & 31);       // 2048..3071
                const int ch  = col - 2048;
                const float bv = bias[col];
#pragma unroll
                for (int rg = 0; rg < 4; ++rg) {
                    // tokens t..t+3, t = m0+i*32+8*rg+4*hi
                    ushort4 w;
                    _Float16 h0 = (_Float16)(accs[i][j][4*rg    ] + bv);
                    _Float16 h1 = (_Float16)(accs[i][j][4*rg + 1] + bv);
                    _Float16 h2 = (_Float16)(accs[i][j][4*rg + 2] + bv);
                    _Float16 h3 = (_Float16)(accs[i][j][4*rg + 3] + bv);
                    w.x = __builtin_bit_cast(unsigned short, h0);
                    w.y = __builtin_bit_cast(unsigned short, h1);
                    w.z = __builtin_bit_cast(unsigned short, h2);
                    w.w = __builtin_bit_cast(unsigned short, h3);
                    const size_t chunk = (size_t)((m0 + i * 32 + 8 * rg) >> 4) * 32 + (ch >> 5);
                    const int interior = ((ch & 31) + 32 * (rg & 1)) * 8 + 4 * hi;
                    *(ushort4*)(vf + chunk * 512 + interior) = w;
                }
            }
        }
    }
}

// ---------------- gemm_s (proven): Wo, BM=128 x BN=128, 512 blocks --------
#define STAGE_S0(NB, KO) { gload16(gA0 + (KO), (NB) + lsA0); gload16(gB0 + (KO), (NB) + lsB0); }
#define STAGE_S1(NB, KO) { gload16(gA1 + (KO), (NB) + lsA1); gload16(gB1 + (KO), (NB) + lsB1); }

#define TILE_S(CB, NB, KT, DOSTG, VW)                                      \
  {                                                                        \
    const size_t ko = (size_t)((KT) + 2) * 1024;                           \
    half8 a0 = *(const half8*)((CB) + oA);                                 \
    half8 a1 = *(const half8*)((CB) + oA + 1024);                          \
    half8 b0v = *(const half8*)((CB) + oB);                                \
    half8 b1v = *(const half8*)((CB) + oB + 1024);                         \
    if (DOSTG) STAGE_S0(NB, ko);                                           \
    __builtin_amdgcn_s_setprio(1);                                         \
    acc00 = MFMA_(a0, b0v, acc00, 0, 0, 0);                                \
    acc01 = MFMA_(a0, b1v, acc01, 0, 0, 0);                                \
    acc10 = MFMA_(a1, b0v, acc10, 0, 0, 0);                                \
    acc11 = MFMA_(a1, b1v, acc11, 0, 0, 0);                                \
    __builtin_amdgcn_s_setprio(0);                                         \
    a0 = *(const half8*)((CB) + oA + 512);                                 \
    a1 = *(const half8*)((CB) + oA + 1536);                                \
    b0v = *(const half8*)((CB) + oB + 512);                                \
    b1v = *(const half8*)((CB) + oB + 1536);                               \
    if (DOSTG) STAGE_S1(NB, ko);                                           \
    __builtin_amdgcn_s_setprio(1);                                         \
    acc00 = MFMA_(a0, b0v, acc00, 0, 0, 0);                                \
    acc01 = MFMA_(a0, b1v, acc01, 0, 0, 0);                                \
    acc10 = MFMA_(a1, b0v, acc10, 0, 0, 0);                                \
    acc11 = MFMA_(a1, b1v, acc11, 0, 0, 0);                                \
    __builtin_amdgcn_s_setprio(0);                                         \
    if ((VW) == 4)      asm volatile("s_waitcnt vmcnt(4) lgkmcnt(0)" ::: "memory"); \
    else if ((VW) == 0) asm volatile("s_waitcnt vmcnt(0) lgkmcnt(0)" ::: "memory"); \
    else                asm volatile("s_waitcnt lgkmcnt(0)" ::: "memory"); \
    asm volatile("s_barrier" ::: "memory");                                \
  }

__global__ __launch_bounds__(256, 2) void gemm_s(
    const u16* __restrict__ Afrag, const u16* __restrict__ Bfrag,
    const float* __restrict__ bias, float* __restrict__ Cout, int Ndim)
{
    __shared__ u16 lds[3][8192];
    const int tid  = threadIdx.x;
    const int lane = tid & 63;
    const int wave = tid >> 6;
    const int wm   = wave >> 1;
    const int wn   = wave & 1;
    const int la8  = lane * 8;

    const int nb  = gridDim.x * gridDim.y;
    int bid = blockIdx.y * gridDim.x + blockIdx.x;
    bid = (bid & 7) * (nb >> 3) + (bid >> 3);
    const int bx = bid % gridDim.x;
    const int by = bid / gridDim.x;

    const u16* gA0 = Afrag + ((size_t)(by*4 + ((wave    )>>1))*64 + ((wave    )&1))*512 + la8;
    const u16* gA1 = Afrag + ((size_t)(by*4 + ((wave+ 4 )>>1))*64 + ((wave+ 4 )&1))*512 + la8;
    const u16* gB0 = Bfrag + ((size_t)(bx*4 + ((wave    )>>1))*64 + ((wave    )&1))*512 + la8;
    const u16* gB1 = Bfrag + ((size_t)(bx*4 + ((wave+ 4 )>>1))*64 + ((wave+ 4 )&1))*512 + la8;
    const int lsA0 = (wave    ) * 512;
    const int lsA1 = (wave + 4) * 512;
    const int lsB0 = 4096 + (wave    ) * 512;
    const int lsB1 = 4096 + (wave + 4) * 512;

    const int oA = wm * 2048 + la8;
    const int oB = 4096 + wn * 2048 + la8;

    u16* b0 = &lds[0][0];
    u16* b1 = &lds[1][0];
    u16* b2 = &lds[2][0];

    STAGE_S0(b0, 0); STAGE_S1(b0, 0);
    STAGE_S0(b1, 1024); STAGE_S1(b1, 1024);
    asm volatile("s_waitcnt vmcnt(4)" ::: "memory");
    asm volatile("s_barrier" ::: "memory");

    f32x16 acc00, acc01, acc10, acc11;
#pragma unroll
    for (int r = 0; r < 16; ++r) { acc00[r] = 0.f; acc01[r] = 0.f; acc10[r] = 0.f; acc11[r] = 0.f; }

#pragma unroll 1
    for (int kt = 0; kt < NT - 2; kt += 3) {
        TILE_S(b0, b2, kt,     1, 4);
        TILE_S(b1, b0, kt + 1, 1, 4);
        TILE_S(b2, b1, kt + 2, 1, 4);
    }
    TILE_S(b0, b2, NT - 2, 0, 0);
    TILE_S(b1, b2, NT - 1, 0, -1);

    const int m0 = by * 128 + wm * 64;
    const int n0 = bx * 128 + wn * 64;
    f32x16 accs[2][2] = {{acc00, acc01}, {acc10, acc11}};
#pragma unroll
    for (int i = 0; i < 2; ++i) {
#pragma unroll
        for (int j = 0; j < 2; ++j) {
            const int col = n0 + j * 32 + (lane & 31);
            const float bv = bias[col];
#pragma unroll
            for (int reg = 0; reg < 16; ++reg) {
                const int row = m0 + i * 32 + (reg & 3) + 8 * (reg >> 2) + 4 * (lane >> 5);
                Cout[(size_t)row * Ndim + col] = accs[i][j][reg] + bv;
            }
        }
    }
}

// ---------------- attn_rm (r8-verified core): MFMA windowed attention -----
// 1 wave / 32-token tile, 256 blocks (1/CU, fully parallel). Q/K gathered
// from row-major qkh (stride 2048); V from V-frag; ctx -> frag-major.
__global__ __launch_bounds__(64) void attn_rm(
    const u16* __restrict__ qkh, const u16* __restrict__ vf,
    u16* __restrict__ ctxf)
{
    const int l   = threadIdx.x;
    const int q   = l & 31;
    const int hi  = l >> 5;
    const int t0  = blockIdx.x * 32;
    const int t0l = t0 & (T_ - 1);

    // ---- QK^T (two shifted 32-row K tiles) ----
    const int r1 = min(max(t0 - 16 + q, 0), M_ - 1);
    const int r2 = min(max(t0 + 16 + q, 0), M_ - 1);
    const u16* a1p = qkh + (size_t)r1 * QK_STRIDE + 1024 + hi * 8;
    const u16* a2p = qkh + (size_t)r2 * QK_STRIDE + 1024 + hi * 8;
    const u16* qp  = qkh + (size_t)(t0 + q) * QK_STRIDE + hi * 8;

    f32x16 sc1, sc2;
#pragma unroll
    for (int r = 0; r < 16; ++r) { sc1[r] = 0.f; sc2[r] = 0.f; }
#pragma unroll 8
    for (int ks = 0; ks < 64; ++ks) {
        half8 a1 = LD8_(a1p + ks * 16);
        half8 a2 = LD8_(a2p + ks * 16);
        half8 qb = LD8_(qp  + ks * 16);
        sc1 = MFMA_(a1, qb, sc1, 0, 0, 0);
        sc2 = MFMA_(a2, qb, sc2, 0, 0, 0);
    }

    // ---- merge half-split columns via lane^32 ----
    float px1[16], px2[16];
#pragma unroll
    for (int r = 0; r < 16; ++r) {
        px1[r] = __shfl_xor(sc1[r], 32);
        px2[r] = __shfl_xor(sc2[r], 32);
    }

    // ---- assemble s[p], p = j_abs - (t0-16); mask + scale ----
    const int plo = max(q + 8, 16 - t0l);
    const int phi = min(q + 24, (T_ + 15) - t0l);
    float s[64];
#pragma unroll
    for (int p = 0; p < 64; ++p) {
        const int row = p & 31;
        const int h   = (row >> 2) & 1;
        const int rg  = (row & 3) + 4 * (row >> 3);
        const float own = (p < 32) ? sc1[rg] : sc2[rg];
        const float oth = (p < 32) ? px1[rg] : px2[rg];
        const float v = (h == hi) ? own : oth;
        s[p] = (p >= plo && p <= phi) ? v * 0.03125f : -3.0e38f;
    }

    // ---- per-lane softmax ----
    float mx = s[0];
#pragma unroll
    for (int p = 1; p < 64; ++p) mx = fmaxf(mx, s[p]);
    float den = 0.f;
#pragma unroll
    for (int p = 0; p < 64; ++p) { const float w = __expf(s[p] - mx); s[p] = w; den += w; }
    const float inv = 1.f / den;

    // ---- pack P -> fp16 A-frags ----
    half8 pa0, pa1, pa2, pa3;
#pragma unroll
    for (int e = 0; e < 8; ++e) {
        pa0[e] = (_Float16)((hi ? s[ 8 + e] : s[ 0 + e]) * inv);
        pa1[e] = (_Float16)((hi ? s[24 + e] : s[16 + e]) * inv);
        pa2[e] = (_Float16)((hi ? s[40 + e] : s[32 + e]) * inv);
        pa3[e] = (_Float16)((hi ? s[56 + e] : s[48 + e]) * inv);
    }

    // ---- PV: 4 token-16 k-slices x 32 ch-chunks; ctx -> frag-major ----
    const int s0i = (t0 - 16) >> 4;
    const u16* vb0p = vf + (size_t)min(max(s0i    , 0), M_/16 - 1) * 16384 + l * 8;
    const u16* vb1p = vf + (size_t)min(max(s0i + 1, 0), M_/16 - 1) * 16384 + l * 8;
    const u16* vb2p = vf + (size_t)min(max(s0i + 2, 0), M_/16 - 1) * 16384 + l * 8;
    const u16* vb3p = vf + (size_t)min(max(s0i + 3, 0), M_/16 - 1) * 16384 + l * 8;
    const size_t ctxb = (size_t)(t0 >> 5) * 32768;
    const int lpo = 32 * ((l >> 3) & 1);
    const int e7  = l & 7;
#pragma unroll 2
    for (int n = 0; n < 32; ++n) {
        half8 v0 = LD8_(vb0p + n * 512);
        half8 v1 = LD8_(vb1p + n * 512);
        half8 v2 = LD8_(vb2p + n * 512);
        half8 v3 = LD8_(vb3p + n * 512);
        f32x16 o;
#pragma unroll
        for (int r = 0; r < 16; ++r) o[r] = 0.f;
        o = MFMA_(pa0, v0, o, 0, 0, 0);
        o = MFMA_(pa1, v1, o, 0, 0, 0);
        o = MFMA_(pa2, v2, o, 0, 0, 0);
        o = MFMA_(pa3, v3, o, 0, 0, 0);
        u16* cp = ctxf + ctxb + (size_t)(2 * n + (q >> 4)) * 512 + e7;
#pragma unroll
        for (int r = 0; r < 16; ++r) {
            const int mrow = (r & 3) + 8 * (r >> 2) + 4 * hi;
            _Float16 hv = (_Float16)o[r];
            cp[(mrow + lpo) * 8] = __builtin_bit_cast(unsigned short, hv);
        }
    }
}

// ---------------- host launch ----------------
extern "C" void kernel_launch(void* const* d_in, const int* in_sizes, int n_in,
                              void* d_out, int out_size, void* d_ws, size_t ws_size,
                              hipStream_t stream) {
    const float* x  = (const float*)d_in[0];
    const float* Wq = (const float*)d_in[1];
    const float* bq = (const float*)d_in[2];
    const float* Wk = (const float*)d_in[3];
    const float* bk = (const float*)d_in[4];
    const float* Wv = (const float*)d_in[5];
    const float* bv = (const float*)d_in[6];
    const float* Wo = (const float*)d_in[7];
    const float* bo = (const float*)d_in[8];
    float* out = (float*)d_out;

    const size_t MC = (size_t)M_ * C_;              // 8M u16
    u16* xf   = (u16*)d_ws;                         // 8M  (x frag)
    u16* wfq  = xf   + MC;                          // 3M  (Wq;Wk;Wv frag)
    u16* wfo  = wfq  + 3 * (size_t)C_ * C_;         // 1M  (Wo frag)
    u16* qkh  = wfo  + (size_t)C_ * C_;             // 16M (row-major Q|K)
    u16* vf   = qkh  + (size_t)M_ * QK_STRIDE;      // 8M  (V-frag)
    u16* ctxf = vf   + MC;                          // 8M  (frag-major)
    float* bcat = (float*)(ctxf + MC);              // 3072 floats

    prologue2<<<3084, 256, 0, stream>>>(x, Wq, Wk, Wv, Wo, bq, bk, bv,
                                        xf, wfq, wfo, bcat);

    dim3 gqkv(3072 / 128, M_ / 256);   // (24, 32) = 768 blocks, 2/CU
    gemm_p2<<<gqkv, 256, 0, stream>>>(xf, wfq, bcat, qkh, vf);

    attn_rm<<<M_ / 32, 64, 0, stream>>>(qkh, vf, ctxf);

    dim3 go(C_ / 128, M_ / 128);       // (8, 64) = 512 blocks, 2/CU
    gemm_s<<<go, 256, 0, stream>>>(ctxf, wfo, bo, out, C_);
}